// Round 12
// baseline (224.753 us; speedup 1.0000x reference)
//
#include <hip/hip_runtime.h>
#include <hip/hip_bf16.h>

#define GLOBAL_AS __attribute__((address_space(1)))
#define LDS_AS    __attribute__((address_space(3)))

typedef __bf16 bf16x8 __attribute__((ext_vector_type(8)));
typedef float  f32x4  __attribute__((ext_vector_type(4)));

constexpr int BATCH = 8192;           // M
constexpr int IN    = 1024;
constexpr int OUT   = 1024;           // N
constexpr int KDIM  = IN * 4;         // 4096
constexpr int BM = 128, BN = 128, BK = 64;
constexpr int NKT  = KDIM / BK;       // 64 K-tiles
constexpr int LDSBUF = 8192;          // ushorts per buffer: B-tile ONLY (16 KB)

__constant__ int ROWOFF_[4] = {0, 16, 64, 80};

// round-to-nearest-even float -> bf16 bits (prep_b only)
__device__ __forceinline__ unsigned short f2bf(float f) {
    union { float f; unsigned u; } v; v.f = f;
    unsigned r = v.u + 0x7fffu + ((v.u >> 16) & 1u);
    return (unsigned short)(r >> 16);
}
__device__ __forceinline__ unsigned pk(unsigned short a, unsigned short b) {
    return (unsigned)a | ((unsigned)b << 16);
}

// B-side prep (unchanged, ran in R7..R11).
// B_big[o, 4i+k] = {W[o,i], C[o,i,1..3]} bf16; be[o] = bias[o] + sum_i C[o,i,0].
__global__ __launch_bounds__(256) void prep_b(const float* __restrict__ W,
                                              const float* __restrict__ C,
                                              const float* __restrict__ bias,
                                              unsigned short* __restrict__ Bb,
                                              float* __restrict__ be) {
    const int o = blockIdx.x, t = threadIdx.x;
    const int i0 = t * 4;
    const float4* c4 = reinterpret_cast<const float4*>(C + ((size_t)o * IN + i0) * 4);
    float4 w4 = *reinterpret_cast<const float4*>(W + (size_t)o * IN + i0);
    float wv[4] = {w4.x, w4.y, w4.z, w4.w};
    float s = 0.f;
    unsigned d[8];
#pragma unroll
    for (int j = 0; j < 4; ++j) {
        float4 c = c4[j];
        s += c.x;                                  // x^0 term -> bias
        d[2*j]   = pk(f2bf(wv[j]), f2bf(c.y));
        d[2*j+1] = pk(f2bf(c.z),   f2bf(c.w));
    }
    uint4* dst = reinterpret_cast<uint4*>(Bb + (size_t)o * KDIM + i0 * 4);
    dst[0] = make_uint4(d[0], d[1], d[2], d[3]);
    dst[1] = make_uint4(d[4], d[5], d[6], d[7]);
#pragma unroll
    for (int off = 32; off > 0; off >>= 1) s += __shfl_down(s, off, 64);
    __shared__ float red[4];
    if ((t & 63) == 0) red[t >> 6] = s;
    __syncthreads();
    if (t == 0) be[o] = bias[o] + red[0] + red[1] + red[2] + red[3];
}

// Fused KAN GEMM with A ENTIRELY IN REGISTERS (no A-LDS path at all).
//
// Key facts (derived from the verified LDS-content mapping of R6..R11):
//   af[kk][mi] for lane (l15,quad) = inputs i0,i0+1 of row r, powers 0..3 each,
//   where r = bm*128 + wr*32 + ROWOFF[mi] + l15 and i0 = kt*16 + kk*8 + 2*quad.
//   So each lane gathers ONE float2 of raw x per fragment (8 loads/tile),
//   expands with the R11-proven 9-op asm sequence (bit-identical output),
//   and feeds MFMA directly -- A never touches LDS.
// Wins: LDS traffic per CU per tile halves (128->64 KB: B only); no ds_write,
//   no lgkm coupling; LDS/buffer 48->16 KB, enabling 128x128 tiles with
//   2 INDEPENDENT blocks/CU (grid 512, 256 thr) -- barrier decoupling.
// Cost: expansion duplicated 2x across wc-waves (trans+VALU ~900 cyc/SIMD/tile,
//   under the 1242-cyc MFMA shadow; separate pipes co-issue per m114).
//
// vmcnt ledger: intra-tile vmem = x-gather 8 (dwordx2) + STAGE_B 4 = 12.
//   Boundary vmcnt(12) therefore retires EVERYTHING issued before this tile
//   (incl. B(kt+1)) regardless of intra-tile issue order. kt==62: 8 (no stage).
//   No lgkm at boundaries (no LDS writes from VALU; ds_reads drain via MFMA deps
//   before each wave's barrier arrival -- R6 argument).
__global__ __launch_bounds__(256, 2) void gemm_kan(
        const float* __restrict__ x,
        const unsigned short* __restrict__ Bb,
        const float* __restrict__ be,
        float* __restrict__ out) {
    extern __shared__ unsigned short smem[];   // 3 * 8192 ushorts = 48 KB

    const int t    = threadIdx.x;              // 0..255 (4 waves)
    const int l    = blockIdx.x;               // 0..511
    const int bm   = l & 63;                   // 0..63 ; bm-sharers on same XCD
    const int bn   = l >> 6;                   // 0..7
    const int lane = t & 63;
    const int wave = t >> 6;                   // 0..3
    const int wr   = wave >> 1;                // 0..1 : M half
    const int wc   = wave & 1;                 // 0..1 : N half
    const int l15  = lane & 15;
    const int quad = lane >> 4;
    const int x7   = l15 & 7;

    // ---- B staging (gload_lds, pre-swizzled global source; LDS dest linear)
    const unsigned short* bP[4];
#pragma unroll
    for (int i = 0; i < 4; ++i) {
        int ch = i * 256 + t, r = ch >> 3, g = (ch & 7) ^ (r & 7);
        bP[i] = Bb + (size_t)(bn * BN + r) * KDIM + g * 8;
    }

    // ---- x gather base: row = bm*BM + wr*32 + ROWOFF[mi] + l15, col = 2*quad
    const float* xq = x + (size_t)(bm * BM + wr * 32 + l15) * IN + 2 * quad;

    // ---- B ds_read base (B at offset 0 of each buffer)
    const int bRd = (wc * 64 + l15) * 64;

    f32x4 acc[4][4];
    const f32x4 zero = {0.f, 0.f, 0.f, 0.f};
#pragma unroll
    for (int i = 0; i < 4; ++i)
#pragma unroll
        for (int j = 0; j < 4; ++j) acc[i][j] = zero;

#define STAGE_B(tile, buf) do {                                                        \
    _Pragma("unroll")                                                                  \
    for (int i_ = 0; i_ < 4; ++i_)                                                     \
        __builtin_amdgcn_global_load_lds(                                              \
            (const GLOBAL_AS void*)(bP[i_] + (size_t)(tile) * BK),                     \
            (LDS_AS void*)(smem + (buf) * LDSBUF + (i_ * 256 + t) * 8), 16, 0, 0);     \
} while (0)

    // x-gather for one tile: 8 x dwordx2 (indices all compile-time via unroll)
#define XLOAD(dst, tile) do {                                                          \
    _Pragma("unroll")                                                                  \
    for (int mi_ = 0; mi_ < 4; ++mi_)                                                  \
        _Pragma("unroll")                                                              \
        for (int kk_ = 0; kk_ < 2; ++kk_)                                              \
            (dst)[mi_][kk_] = *reinterpret_cast<const float2*>(                        \
                xq + (size_t)ROWOFF_[mi_] * IN + (tile) * 16 + kk_ * 8);               \
} while (0)

    // expansion: float2 -> 8 bf16 {silu,x,x^2,x^3}x2 -- bit-identical to R11
#define EXPAND(dst, xv2) do {                                                          \
    float xa_[2] = {(xv2).x, (xv2).y};                                                 \
    unsigned u_[4];                                                                    \
    _Pragma("unroll")                                                                  \
    for (int e_ = 0; e_ < 2; ++e_) {                                                   \
        float xv_ = xa_[e_];                                                           \
        float m_  = xv_ * -1.44269504088896f;      /* -x*log2(e) */                    \
        float ex_, r_;                                                                 \
        asm("v_exp_f32 %0, %1" : "=v"(ex_) : "v"(m_));   /* e^-x */                    \
        float a_  = 1.0f + ex_;                                                        \
        asm("v_rcp_f32 %0, %1" : "=v"(r_) : "v"(a_));                                  \
        float s_  = xv_ * r_;                                                          \
        float x2_ = xv_ * xv_;                                                         \
        float x3_ = x2_ * xv_;                                                         \
        asm("v_cvt_pk_bf16_f32 %0, %1, %2" : "=v"(u_[2*e_])   : "v"(s_),  "v"(xv_));   \
        asm("v_cvt_pk_bf16_f32 %0, %1, %2" : "=v"(u_[2*e_+1]) : "v"(x2_), "v"(x3_));   \
    }                                                                                  \
    __builtin_memcpy(&(dst), u_, 16);                                                  \
} while (0)

    // ---- prologue: x(0) in regs; B(0),B(1) staged
    float2 xr[4][2];
    XLOAD(xr, 0);
    STAGE_B(0, 0);
    STAGE_B(1, 1);
    asm volatile("s_waitcnt vmcnt(4)" ::: "memory");   // B(0) landed; B(1) in flight
    __builtin_amdgcn_s_barrier();

    int cb = 0;
    for (int kt = 0; kt < NKT; ++kt) {
        const unsigned short* sb = smem + cb * LDSBUF;
        const int nb = (cb >= 1) ? cb - 1 : 2;         // buffer for tile kt+2

        // next-tile x gather (latency hidden under this tile's compute)
        float2 xn[4][2];
        if (kt + 1 < NKT) XLOAD(xn, kt + 1);

        // expand current x -> A-fragments (registers only)
        bf16x8 af[2][4];
#pragma unroll
        for (int kk = 0; kk < 2; ++kk)
#pragma unroll
            for (int mi = 0; mi < 4; ++mi)
                EXPAND(af[kk][mi], xr[mi][kk]);

        if (kt + 2 < NKT) STAGE_B(kt + 2, nb);

#pragma unroll
        for (int kk = 0; kk < 2; ++kk) {
            const int ck = ((kk * 4 + quad) ^ x7) * 8;
            bf16x8 bv[4];
#pragma unroll
            for (int ni = 0; ni < 4; ++ni)
                bv[ni] = *reinterpret_cast<const bf16x8*>(sb + bRd + ni * 1024 + ck);
#pragma unroll
            for (int mi = 0; mi < 4; ++mi)
#pragma unroll
                for (int ni = 0; ni < 4; ++ni)
                    acc[mi][ni] = __builtin_amdgcn_mfma_f32_16x16x32_bf16(
                        af[kk][mi], bv[ni], acc[mi][ni], 0, 0, 0);
        }

        // rotate x regs
        if (kt + 1 < NKT) {
#pragma unroll
            for (int mi = 0; mi < 4; ++mi)
#pragma unroll
                for (int kk = 0; kk < 2; ++kk) xr[mi][kk] = xn[mi][kk];
        }

        // boundary: retire everything issued BEFORE this tile (incl. B(kt+1));
        // this tile's 12 (or 8) vmem ops stay in flight.
        if (kt < NKT - 2) {
            asm volatile("s_waitcnt vmcnt(12)" ::: "memory");
            __builtin_amdgcn_s_barrier();
        } else if (kt == NKT - 2) {
            asm volatile("s_waitcnt vmcnt(8)" ::: "memory");   // B(63) landed
            __builtin_amdgcn_s_barrier();
        }
        cb = (cb == 2) ? 0 : cb + 1;
    }

#undef STAGE_B
#undef XLOAD
#undef EXPAND

    // ---- epilogue: C/D layout col = lane&15, row = quad*4 + reg
    float bev[4];
#pragma unroll
    for (int ni = 0; ni < 4; ++ni)
        bev[ni] = be[bn * BN + wc * 64 + ni * 16 + l15];

#pragma unroll
    for (int mg = 0; mg < 4; ++mg) {
        const int grow = bm * BM + (mg >> 1) * 64 + wr * 32 + (mg & 1) * 16 + quad * 4;
#pragma unroll
        for (int ni = 0; ni < 4; ++ni) {
            const int gcol = bn * BN + wc * 64 + ni * 16 + l15;
            float* po = out + (size_t)grow * OUT + gcol;
#pragma unroll
            for (int r = 0; r < 4; ++r)
                po[(size_t)r * OUT] = acc[mg][ni][r] + bev[ni];
        }
    }
}

extern "C" void kernel_launch(void* const* d_in, const int* in_sizes, int n_in,
                              void* d_out, int out_size, void* d_ws, size_t ws_size,
                              hipStream_t stream) {
    const float* x    = (const float*)d_in[0];   // [8192,1024]
    const float* W    = (const float*)d_in[1];   // [1024,1024]
    const float* C    = (const float*)d_in[2];   // [1024,1024,4]
    const float* bias = (const float*)d_in[3];   // [1024]
    float* out = (float*)d_out;

    unsigned short* Bb = (unsigned short*)d_ws;                    // 8 MB
    float*          be = (float*)(Bb + (size_t)OUT * KDIM);        // 4 KB

    constexpr int LDS_BYTES = 3 * LDSBUF * 2;                      // 49152 = 48 KB
    static bool inited = false;
    if (!inited) {
        hipFuncSetAttribute(reinterpret_cast<const void*>(&gemm_kan),
                            hipFuncAttributeMaxDynamicSharedMemorySize, LDS_BYTES);
        inited = true;
    }

    prep_b<<<dim3(1024), dim3(256), 0, stream>>>(W, C, bias, Bb, be);

    gemm_kan<<<dim3(512), dim3(256), LDS_BYTES, stream>>>(x, Bb, be, out);
}

// Round 13
// 168.148 us; speedup vs baseline: 1.3366x; 1.3366x over previous
//
#include <hip/hip_runtime.h>
#include <hip/hip_bf16.h>

#define GLOBAL_AS __attribute__((address_space(1)))
#define LDS_AS    __attribute__((address_space(3)))

typedef __bf16 bf16x8 __attribute__((ext_vector_type(8)));
typedef float  f32x4  __attribute__((ext_vector_type(4)));

constexpr int BATCH = 8192;           // M
constexpr int IN    = 1024;
constexpr int OUT   = 1024;           // N
constexpr int KDIM  = IN * 4;         // 4096 (4 "powers" per input)
constexpr int BM = 128, BN = 256, BK = 64;
constexpr int NKT  = KDIM / BK;       // 64 K-tiles
constexpr int LDSBUF = 24576;         // ushort elems per buffer: A 8192 + B 16384 (48 KB)

// round-to-nearest-even float -> bf16 bits (prep_b only; gemm uses HW pair-cvt)
__device__ __forceinline__ unsigned short f2bf(float f) {
    union { float f; unsigned u; } v; v.f = f;
    unsigned r = v.u + 0x7fffu + ((v.u >> 16) & 1u);
    return (unsigned short)(r >> 16);
}
__device__ __forceinline__ unsigned pk(unsigned short a, unsigned short b) {
    return (unsigned)a | ((unsigned)b << 16);
}

// B-side prep (A-expansion fused into the gemm).
// B_big[o, 4i+k] = {W[o,i], C[o,i,1..3]} bf16; be[o] = bias[o] + sum_i C[o,i,0].
__global__ __launch_bounds__(256) void prep_b(const float* __restrict__ W,
                                              const float* __restrict__ C,
                                              const float* __restrict__ bias,
                                              unsigned short* __restrict__ Bb,
                                              float* __restrict__ be) {
    const int o = blockIdx.x, t = threadIdx.x;
    const int i0 = t * 4;
    const float4* c4 = reinterpret_cast<const float4*>(C + ((size_t)o * IN + i0) * 4);
    float4 w4 = *reinterpret_cast<const float4*>(W + (size_t)o * IN + i0);
    float wv[4] = {w4.x, w4.y, w4.z, w4.w};
    float s = 0.f;
    unsigned d[8];
#pragma unroll
    for (int j = 0; j < 4; ++j) {
        float4 c = c4[j];
        s += c.x;                                  // x^0 term -> bias
        d[2*j]   = pk(f2bf(wv[j]), f2bf(c.y));
        d[2*j+1] = pk(f2bf(c.z),   f2bf(c.w));
    }
    uint4* dst = reinterpret_cast<uint4*>(Bb + (size_t)o * KDIM + i0 * 4);
    dst[0] = make_uint4(d[0], d[1], d[2], d[3]);
    dst[1] = make_uint4(d[4], d[5], d[6], d[7]);
#pragma unroll
    for (int off = 32; off > 0; off >>= 1) s += __shfl_down(s, off, 64);
    __shared__ float red[4];
    if ((t & 63) == 0) red[t >> 6] = s;
    __syncthreads();
    if (t == 0) be[o] = bias[o] + red[0] + red[1] + red[2] + red[3];
}

// Fused KAN GEMM = R11 structure (best verified: gemm 90.4us, total 165.8)
// with ONE change: STAGE_A moved from the boundary shadow to BETWEEN the
// kk=0 and kk=1 MFMA clusters.
//
// Safety of mid-tile STAGE_A into nb = buf(kt-1): every wave's ds_reads of
// buf(kt-1) retired at its lgkm gate before its tile-(kt-1) barrier arrival,
// so after that barrier no wave reads buf(kt-1) until restaged => writing it
// anywhere inside tile kt is race-free (same argument that justified R11's
// placement). Ledger unchanged (STAGE_A has no vmem ops). Boundary lgkmcnt(0)
// now drains ds_writes issued half a tile earlier (cheaper boundary), and the
// expansion VALU/trans sits where the OTHER wave on the SIMD is mid-MFMA.
//
// R12 lesson encoded here: A staging must stay on the LDS path (gload-style
// layout + ds_write); per-fragment x gathers from global are 16-segment
// scatters on the MFMA critical path (90.4 -> 155.9us).
//
// vmcnt ledger (per wave): steady boundary queue = [B(kt+1)x4] + {x(kt+3),
// B(kt+2)x4} -> vmcnt(5); kt==61 -> vmcnt(4); kt==62 -> vmcnt(0).
__global__ __launch_bounds__(512, 2) void gemm_kan(
        const float* __restrict__ x,
        const unsigned short* __restrict__ Bb,
        const float* __restrict__ be,
        float* __restrict__ out) {
    extern __shared__ unsigned short smem[];   // 3 * 24576 ushorts = 144 KB

    const int t    = threadIdx.x;
    const int l    = blockIdx.x;               // 0..255
    const int bm   = l & 63;                   // 0..63
    const int bn   = l >> 6;                   // 0..3
    const int lane = t & 63;
    const int wave = t >> 6;                   // 0..7
    const int wr   = wave >> 2;                // 0..1 : M half
    const int wc   = wave & 3;                 // 0..3 : N quarter
    const int l15  = lane & 15;
    const int quad = lane >> 4;
    const int x7   = l15 & 7;

    // ---- B staging (gload_lds, pre-swizzled global source; LDS dest linear)
    const unsigned short* bP[4];
#pragma unroll
    for (int i = 0; i < 4; ++i) {
        int ch = i * 512 + t, r = ch >> 3, g = (ch & 7) ^ (r & 7);
        bP[i] = Bb + (size_t)(bn * BN + r) * KDIM + g * 8;
    }

    // ---- A expansion (reg -> swizzled ds_write): thread t owns row t>>2, x-quad t&3
    const int arow  = t >> 2;                  // 0..127
    const int axi   = t & 3;                   // which 4 of the 16 x's in the tile
    const int aoff0 = arow * 64 + (((axi * 2)     ^ (arow & 7)) * 8);
    const int aoff1 = arow * 64 + (((axi * 2 + 1) ^ (arow & 7)) * 8);
    const float4* xp = reinterpret_cast<const float4*>(
        x + (size_t)(bm * BM + arow) * IN + axi * 4);   // tile kt -> xp[kt*4]

    // ---- ds_read bases (ushort elements)
    const int aRd = (wr * 32 + l15) * 64;            // A region at offset 0
    const int bRd = 8192 + (wc * 64 + l15) * 64;     // B region at offset 8192

    f32x4 acc[4][4];
    const f32x4 zero = {0.f, 0.f, 0.f, 0.f};
#pragma unroll
    for (int i = 0; i < 4; ++i)
#pragma unroll
        for (int j = 0; j < 4; ++j) acc[i][j] = zero;

#define STAGE_B(tile, buf) do {                                                        \
    _Pragma("unroll")                                                                  \
    for (int i_ = 0; i_ < 4; ++i_)                                                     \
        __builtin_amdgcn_global_load_lds(                                              \
            (const GLOBAL_AS void*)(bP[i_] + (size_t)(tile) * BK),                     \
            (LDS_AS void*)(smem + (buf) * LDSBUF + 8192 + (i_ * 512 + t) * 8),         \
            16, 0, 0);                                                                 \
} while (0)

    // slim expansion: {silu, x, x^2, x^3}, 9 VALU/element via inline-asm VOP1/VOP3
#define STAGE_A(buf, v) do {                                                           \
    float e_[4] = {(v).x, (v).y, (v).z, (v).w};                                        \
    unsigned d_[8];                                                                    \
    _Pragma("unroll")                                                                  \
    for (int j = 0; j < 4; ++j) {                                                      \
        float xv_ = e_[j];                                                             \
        float m_  = xv_ * -1.44269504088896f;       /* -x*log2(e) */                   \
        float ex_, r_;                                                                 \
        asm("v_exp_f32 %0, %1" : "=v"(ex_) : "v"(m_));   /* 2^m = e^-x */              \
        float a_  = 1.0f + ex_;                                                        \
        asm("v_rcp_f32 %0, %1" : "=v"(r_) : "v"(a_));                                  \
        float s_  = xv_ * r_;                                                          \
        float x2_ = xv_ * xv_;                                                         \
        float x3_ = x2_ * xv_;                                                         \
        asm("v_cvt_pk_bf16_f32 %0, %1, %2" : "=v"(d_[2*j])   : "v"(s_),  "v"(xv_));    \
        asm("v_cvt_pk_bf16_f32 %0, %1, %2" : "=v"(d_[2*j+1]) : "v"(x2_), "v"(x3_));    \
    }                                                                                  \
    unsigned short* ab_ = smem + (buf) * LDSBUF;                                       \
    *reinterpret_cast<uint4*>(ab_ + aoff0) = make_uint4(d_[0], d_[1], d_[2], d_[3]);   \
    *reinterpret_cast<uint4*>(ab_ + aoff1) = make_uint4(d_[4], d_[5], d_[6], d_[7]);   \
} while (0)

    // ---- prologue: A(0),A(1) expanded; B(0),B(1) staged; x(2) in flight.
    float4 xa   = xp[0];
    float4 xb   = xp[4];
    float4 xcur = xp[8];                       // x for tile 2
    float4 xnext = xcur;                       // rotation register
    STAGE_B(0, 0);
    STAGE_B(1, 1);
    STAGE_A(0, xa);
    STAGE_A(1, xb);
    // vmcnt(4) robust to compiler placement of the x(2) issue: the oldest
    // 5 retired always include B(0)x4. lgkmcnt(0) drains our ds_writes.
    asm volatile("s_waitcnt vmcnt(4) lgkmcnt(0)" ::: "memory");
    __builtin_amdgcn_s_barrier();

    int cb = 0;
    for (int kt = 0; kt < NKT; ++kt) {
        const unsigned short* sb = smem + cb * LDSBUF;
        const int nb = (cb >= 1) ? cb - 1 : 2;         // buffer for tile kt+2
        const bool pf = (kt + 2) < NKT;

        if (kt + 3 < NKT) xnext = xp[(kt + 3) * 4];    // x for tile kt+3
        if (pf) STAGE_B(kt + 2, nb);

        // ---- kk = 0 ----
        {
            const int ck = (quad ^ x7) * 8;
            bf16x8 af[4], bv[4];
            af[0] = *reinterpret_cast<const bf16x8*>(sb + aRd + ck);
            af[1] = *reinterpret_cast<const bf16x8*>(sb + aRd + 1024 + ck);
            af[2] = *reinterpret_cast<const bf16x8*>(sb + aRd + 4096 + ck);
            af[3] = *reinterpret_cast<const bf16x8*>(sb + aRd + 5120 + ck);
#pragma unroll
            for (int ni = 0; ni < 4; ++ni)
                bv[ni] = *reinterpret_cast<const bf16x8*>(sb + bRd + ni * 1024 + ck);
#pragma unroll
            for (int mi = 0; mi < 4; ++mi)
#pragma unroll
                for (int ni = 0; ni < 4; ++ni)
                    acc[mi][ni] = __builtin_amdgcn_mfma_f32_16x16x32_bf16(
                        af[mi], bv[ni], acc[mi][ni], 0, 0, 0);
        }

        // ---- mid-tile: expand A(kt+2) into nb (safe: no wave reads buf(kt-1)
        // during tile kt; see header). Expansion overlaps the co-resident
        // wave's MFMA clusters; ds_writes drain at the boundary lgkmcnt(0).
        if (pf) {
            STAGE_A(nb, xcur);
            xcur = xnext;
        }

        // ---- kk = 1 ----
        {
            const int ck = ((4 + quad) ^ x7) * 8;
            bf16x8 af[4], bv[4];
            af[0] = *reinterpret_cast<const bf16x8*>(sb + aRd + ck);
            af[1] = *reinterpret_cast<const bf16x8*>(sb + aRd + 1024 + ck);
            af[2] = *reinterpret_cast<const bf16x8*>(sb + aRd + 4096 + ck);
            af[3] = *reinterpret_cast<const bf16x8*>(sb + aRd + 5120 + ck);
#pragma unroll
            for (int ni = 0; ni < 4; ++ni)
                bv[ni] = *reinterpret_cast<const bf16x8*>(sb + bRd + ni * 1024 + ck);
#pragma unroll
            for (int mi = 0; mi < 4; ++mi)
#pragma unroll
                for (int ni = 0; ni < 4; ++ni)
                    acc[mi][ni] = __builtin_amdgcn_mfma_f32_16x16x32_bf16(
                        af[mi], bv[ni], acc[mi][ni], 0, 0, 0);
        }

        // ---- boundary: B(kt+1) landed; our ds_writes drained; prefetch in flight
        if (kt < NKT - 3) {
            asm volatile("s_waitcnt vmcnt(5) lgkmcnt(0)" ::: "memory");
            __builtin_amdgcn_s_barrier();
        } else if (kt == NKT - 3) {            // kt==61: no x(64) issued this tile
            asm volatile("s_waitcnt vmcnt(4) lgkmcnt(0)" ::: "memory");
            __builtin_amdgcn_s_barrier();
        } else if (kt == NKT - 2) {            // kt==62: drain B(63)
            asm volatile("s_waitcnt vmcnt(0) lgkmcnt(0)" ::: "memory");
            __builtin_amdgcn_s_barrier();
        }
        cb = (cb == 2) ? 0 : cb + 1;
    }

#undef STAGE_A
#undef STAGE_B

    // ---- epilogue: C/D layout col = lane&15, row = quad*4 + reg
    float bev[4];
#pragma unroll
    for (int ni = 0; ni < 4; ++ni)
        bev[ni] = be[bn * BN + wc * 64 + ni * 16 + l15];

#pragma unroll
    for (int mg = 0; mg < 4; ++mg) {
        const int grow = bm * BM + (mg >> 1) * 64 + wr * 32 + (mg & 1) * 16 + quad * 4;
#pragma unroll
        for (int ni = 0; ni < 4; ++ni) {
            const int gcol = bn * BN + wc * 64 + ni * 16 + l15;
            float* po = out + (size_t)grow * OUT + gcol;
#pragma unroll
            for (int r = 0; r < 4; ++r)
                po[(size_t)r * OUT] = acc[mg][ni][r] + bev[ni];
        }
    }
}

extern "C" void kernel_launch(void* const* d_in, const int* in_sizes, int n_in,
                              void* d_out, int out_size, void* d_ws, size_t ws_size,
                              hipStream_t stream) {
    const float* x    = (const float*)d_in[0];   // [8192,1024]
    const float* W    = (const float*)d_in[1];   // [1024,1024]
    const float* C    = (const float*)d_in[2];   // [1024,1024,4]
    const float* bias = (const float*)d_in[3];   // [1024]
    float* out = (float*)d_out;

    unsigned short* Bb = (unsigned short*)d_ws;                    // 8 MB
    float*          be = (float*)(Bb + (size_t)OUT * KDIM);        // 4 KB

    constexpr int LDS_BYTES = 3 * LDSBUF * 2;                      // 147456 = 144 KB
    static bool inited = false;
    if (!inited) {
        hipFuncSetAttribute(reinterpret_cast<const void*>(&gemm_kan),
                            hipFuncAttributeMaxDynamicSharedMemorySize, LDS_BYTES);
        inited = true;
    }

    prep_b<<<dim3(1024), dim3(256), 0, stream>>>(W, C, bias, Bb, be);

    gemm_kan<<<dim3(256), dim3(512), LDS_BYTES, stream>>>(x, Bb, be, out);
}

// Round 14
// 162.077 us; speedup vs baseline: 1.3867x; 1.0375x over previous
//
#include <hip/hip_runtime.h>
#include <hip/hip_bf16.h>

#define GLOBAL_AS __attribute__((address_space(1)))
#define LDS_AS    __attribute__((address_space(3)))

typedef __bf16 bf16x8 __attribute__((ext_vector_type(8)));
typedef float  f32x4  __attribute__((ext_vector_type(4)));

constexpr int BATCH = 8192;           // M
constexpr int IN    = 1024;
constexpr int OUT   = 1024;           // N
constexpr int KDIM  = IN * 4;         // 4096 (4 "powers" per input)
constexpr int BM = 128, BN = 256, BK = 64;
constexpr int NKT  = KDIM / BK;       // 64 K-tiles (even -> clean 2x unroll)
constexpr int LDSBUF = 24576;         // ushort elems per buffer: A 8192 + B 16384 (48 KB)

// round-to-nearest-even float -> bf16 bits (prep_b only; gemm uses HW pair-cvt)
__device__ __forceinline__ unsigned short f2bf(float f) {
    union { float f; unsigned u; } v; v.f = f;
    unsigned r = v.u + 0x7fffu + ((v.u >> 16) & 1u);
    return (unsigned short)(r >> 16);
}
__device__ __forceinline__ unsigned pk(unsigned short a, unsigned short b) {
    return (unsigned)a | ((unsigned)b << 16);
}

// B-side prep (A-expansion fused into the gemm).
// B_big[o, 4i+k] = {W[o,i], C[o,i,1..3]} bf16; be[o] = bias[o] + sum_i C[o,i,0].
__global__ __launch_bounds__(256) void prep_b(const float* __restrict__ W,
                                              const float* __restrict__ C,
                                              const float* __restrict__ bias,
                                              unsigned short* __restrict__ Bb,
                                              float* __restrict__ be) {
    const int o = blockIdx.x, t = threadIdx.x;
    const int i0 = t * 4;
    const float4* c4 = reinterpret_cast<const float4*>(C + ((size_t)o * IN + i0) * 4);
    float4 w4 = *reinterpret_cast<const float4*>(W + (size_t)o * IN + i0);
    float wv[4] = {w4.x, w4.y, w4.z, w4.w};
    float s = 0.f;
    unsigned d[8];
#pragma unroll
    for (int j = 0; j < 4; ++j) {
        float4 c = c4[j];
        s += c.x;                                  // x^0 term -> bias
        d[2*j]   = pk(f2bf(wv[j]), f2bf(c.y));
        d[2*j+1] = pk(f2bf(c.z),   f2bf(c.w));
    }
    uint4* dst = reinterpret_cast<uint4*>(Bb + (size_t)o * KDIM + i0 * 4);
    dst[0] = make_uint4(d[0], d[1], d[2], d[3]);
    dst[1] = make_uint4(d[4], d[5], d[6], d[7]);
#pragma unroll
    for (int off = 32; off > 0; off >>= 1) s += __shfl_down(s, off, 64);
    __shared__ float red[4];
    if ((t & 63) == 0) red[t >> 6] = s;
    __syncthreads();
    if (t == 0) be[o] = bias[o] + red[0] + red[1] + red[2] + red[3];
}

// Fused KAN GEMM = R11 structure (session best: gemm 90.4us, total 165.8)
// + A-FRAGMENT REGISTER PREFETCH across the barrier.
//
// Mechanism: A(kt+1) is ds_written during tile kt-1's boundary shadow and
// lgkm-drained BEFORE barrier(kt-1) -> readable during all of tile kt (unlike
// B, whose cross-wave gload_lds shares only land at the boundary vmcnt+barrier;
// vmcnt is per-wave, so early B reads would race other waves' staging).
// Prefetching the 8 A-fragments of tile kt+1 into registers during tile kt
// leaves only 8 B ds_reads on the post-barrier critical path (was 16 reads).
// Ping-pong afA/afB via 2x loop unroll -> no register copies, all indices
// compile-time (rule #20). VGPR ~100 <= 128 cap of launch_bounds(512,2).
//
// STAGE_A restored to the boundary shadow (R13's mid-tile placement: -5us).
// R12 lesson: A staging stays on the LDS path (global per-fragment gathers
// are 16-segment scatters, 90->156us).
//
// vmcnt ledger (per wave, unchanged from R11): steady boundary queue =
// [B(kt+1)x4] + {x(kt+3), B(kt+2)x4} -> vmcnt(5); kt==61 -> vmcnt(4);
// kt==62 -> vmcnt(0); kt==63 none. lgkmcnt(0) at each boundary drains this
// wave's A ds_writes (and the A-prefetch reads, already complete).
__global__ __launch_bounds__(512, 2) void gemm_kan(
        const float* __restrict__ x,
        const unsigned short* __restrict__ Bb,
        const float* __restrict__ be,
        float* __restrict__ out) {
    extern __shared__ unsigned short smem[];   // 3 * 24576 ushorts = 144 KB

    const int t    = threadIdx.x;
    const int l    = blockIdx.x;               // 0..255
    const int bm   = l & 63;                   // 0..63
    const int bn   = l >> 6;                   // 0..3
    const int lane = t & 63;
    const int wave = t >> 6;                   // 0..7
    const int wr   = wave >> 2;                // 0..1 : M half
    const int wc   = wave & 3;                 // 0..3 : N quarter
    const int l15  = lane & 15;
    const int quad = lane >> 4;
    const int x7   = l15 & 7;

    // ---- B staging (gload_lds, pre-swizzled global source; LDS dest linear)
    const unsigned short* bP[4];
#pragma unroll
    for (int i = 0; i < 4; ++i) {
        int ch = i * 512 + t, r = ch >> 3, g = (ch & 7) ^ (r & 7);
        bP[i] = Bb + (size_t)(bn * BN + r) * KDIM + g * 8;
    }

    // ---- A expansion (reg -> swizzled ds_write): thread t owns row t>>2, x-quad t&3
    const int arow  = t >> 2;                  // 0..127
    const int axi   = t & 3;                   // which 4 of the 16 x's in the tile
    const int aoff0 = arow * 64 + (((axi * 2)     ^ (arow & 7)) * 8);
    const int aoff1 = arow * 64 + (((axi * 2 + 1) ^ (arow & 7)) * 8);
    const float4* xp = reinterpret_cast<const float4*>(
        x + (size_t)(bm * BM + arow) * IN + axi * 4);   // tile kt -> xp[kt*4]

    // ---- ds_read bases (ushort elements)
    const int aRd = (wr * 32 + l15) * 64;            // A region at offset 0
    const int bRd = 8192 + (wc * 64 + l15) * 64;     // B region at offset 8192
    const int ck0 = (quad ^ x7) * 8;                 // kk=0 swizzled chunk
    const int ck1 = ((4 + quad) ^ x7) * 8;           // kk=1 swizzled chunk

    f32x4 acc[4][4];
    const f32x4 zero = {0.f, 0.f, 0.f, 0.f};
#pragma unroll
    for (int i = 0; i < 4; ++i)
#pragma unroll
        for (int j = 0; j < 4; ++j) acc[i][j] = zero;

#define STAGE_B(tile, buf) do {                                                        \
    _Pragma("unroll")                                                                  \
    for (int i_ = 0; i_ < 4; ++i_)                                                     \
        __builtin_amdgcn_global_load_lds(                                              \
            (const GLOBAL_AS void*)(bP[i_] + (size_t)(tile) * BK),                     \
            (LDS_AS void*)(smem + (buf) * LDSBUF + 8192 + (i_ * 512 + t) * 8),         \
            16, 0, 0);                                                                 \
} while (0)

    // slim expansion: {silu, x, x^2, x^3}, 9 VALU/element via inline-asm VOP1/VOP3
#define STAGE_A(buf, v) do {                                                           \
    float e_[4] = {(v).x, (v).y, (v).z, (v).w};                                        \
    unsigned d_[8];                                                                    \
    _Pragma("unroll")                                                                  \
    for (int j = 0; j < 4; ++j) {                                                      \
        float xv_ = e_[j];                                                             \
        float m_  = xv_ * -1.44269504088896f;       /* -x*log2(e) */                   \
        float ex_, r_;                                                                 \
        asm("v_exp_f32 %0, %1" : "=v"(ex_) : "v"(m_));   /* 2^m = e^-x */              \
        float a_  = 1.0f + ex_;                                                        \
        asm("v_rcp_f32 %0, %1" : "=v"(r_) : "v"(a_));                                  \
        float s_  = xv_ * r_;                                                          \
        float x2_ = xv_ * xv_;                                                         \
        float x3_ = x2_ * xv_;                                                         \
        asm("v_cvt_pk_bf16_f32 %0, %1, %2" : "=v"(d_[2*j])   : "v"(s_),  "v"(xv_));    \
        asm("v_cvt_pk_bf16_f32 %0, %1, %2" : "=v"(d_[2*j+1]) : "v"(x2_), "v"(x3_));    \
    }                                                                                  \
    unsigned short* ab_ = smem + (buf) * LDSBUF;                                       \
    *reinterpret_cast<uint4*>(ab_ + aoff0) = make_uint4(d_[0], d_[1], d_[2], d_[3]);   \
    *reinterpret_cast<uint4*>(ab_ + aoff1) = make_uint4(d_[4], d_[5], d_[6], d_[7]);   \
} while (0)

    // read 8 A-fragments of the tile living in LDS buffer `bufp` into DST
#define AFETCH(DST, bufp) do {                                                         \
    const unsigned short* sn_ = smem + (bufp) * LDSBUF;                                \
    (DST)[0][0] = *reinterpret_cast<const bf16x8*>(sn_ + aRd + ck0);                   \
    (DST)[0][1] = *reinterpret_cast<const bf16x8*>(sn_ + aRd + 1024 + ck0);            \
    (DST)[0][2] = *reinterpret_cast<const bf16x8*>(sn_ + aRd + 4096 + ck0);            \
    (DST)[0][3] = *reinterpret_cast<const bf16x8*>(sn_ + aRd + 5120 + ck0);            \
    (DST)[1][0] = *reinterpret_cast<const bf16x8*>(sn_ + aRd + ck1);                   \
    (DST)[1][1] = *reinterpret_cast<const bf16x8*>(sn_ + aRd + 1024 + ck1);            \
    (DST)[1][2] = *reinterpret_cast<const bf16x8*>(sn_ + aRd + 4096 + ck1);            \
    (DST)[1][3] = *reinterpret_cast<const bf16x8*>(sn_ + aRd + 5120 + ck1);            \
} while (0)

    // one K-tile: use AFU (prefetched last tile), prefetch AFF = A(KT+1)
#define TILE_ITER(KT, AFU, AFF) do {                                                   \
    const unsigned short* sb = smem + cb * LDSBUF;                                     \
    const int nxt = (cb == 2) ? 0 : cb + 1;        /* buffer of tile KT+1 */           \
    const int nb  = (cb >= 1) ? cb - 1 : 2;        /* buffer for tile KT+2 */          \
    if ((KT) + 3 < NKT) xnext = xp[((KT) + 3) * 4];                                    \
    if ((KT) + 2 < NKT) STAGE_B((KT) + 2, nb);                                         \
    if ((KT) + 1 < NKT) AFETCH(AFF, nxt);          /* A(KT+1): visible since bar-1 */  \
    _Pragma("unroll")                                                                  \
    for (int kk = 0; kk < 2; ++kk) {                                                   \
        const int ck = kk ? ck1 : ck0;                                                 \
        bf16x8 bv[4];                                                                  \
        _Pragma("unroll")                                                              \
        for (int ni = 0; ni < 4; ++ni)                                                 \
            bv[ni] = *reinterpret_cast<const bf16x8*>(sb + bRd + ni * 1024 + ck);      \
        _Pragma("unroll")                                                              \
        for (int mi = 0; mi < 4; ++mi)                                                 \
            _Pragma("unroll")                                                          \
            for (int ni = 0; ni < 4; ++ni)                                             \
                acc[mi][ni] = __builtin_amdgcn_mfma_f32_16x16x32_bf16(                 \
                    (AFU)[kk][mi], bv[ni], acc[mi][ni], 0, 0, 0);                      \
    }                                                                                  \
    if ((KT) + 2 < NKT) { STAGE_A(nb, xcur); xcur = xnext; }   /* boundary shadow */   \
    if ((KT) < NKT - 3) {                                                              \
        asm volatile("s_waitcnt vmcnt(5) lgkmcnt(0)" ::: "memory");                    \
        __builtin_amdgcn_s_barrier();                                                  \
    } else if ((KT) == NKT - 3) {                                                      \
        asm volatile("s_waitcnt vmcnt(4) lgkmcnt(0)" ::: "memory");                    \
        __builtin_amdgcn_s_barrier();                                                  \
    } else if ((KT) == NKT - 2) {                                                      \
        asm volatile("s_waitcnt vmcnt(0) lgkmcnt(0)" ::: "memory");                    \
        __builtin_amdgcn_s_barrier();                                                  \
    }                                                                                  \
    cb = (cb == 2) ? 0 : cb + 1;                                                       \
} while (0)

    // ---- prologue: A(0),A(1) expanded; B(0),B(1) staged; x(2) in flight.
    float4 xa   = xp[0];
    float4 xb   = xp[4];
    float4 xcur = xp[8];                       // x for tile 2
    float4 xnext = xcur;                       // rotation register
    STAGE_B(0, 0);
    STAGE_B(1, 1);
    STAGE_A(0, xa);
    STAGE_A(1, xb);
    // vmcnt(4) robust to compiler placement of the x(2) issue: the oldest
    // 5 retired always include B(0)x4. lgkmcnt(0) drains our ds_writes.
    asm volatile("s_waitcnt vmcnt(4) lgkmcnt(0)" ::: "memory");
    __builtin_amdgcn_s_barrier();

    bf16x8 afA[2][4], afB[2][4];
    AFETCH(afA, 0);                            // A(0) fragments (buf 0)

    int cb = 0;
    for (int kt = 0; kt < NKT; kt += 2) {      // NKT even -> exact pairing
        TILE_ITER(kt,     afA, afB);
        TILE_ITER(kt + 1, afB, afA);
    }

#undef TILE_ITER
#undef AFETCH
#undef STAGE_A
#undef STAGE_B

    // ---- epilogue: C/D layout col = lane&15, row = quad*4 + reg
    float bev[4];
#pragma unroll
    for (int ni = 0; ni < 4; ++ni)
        bev[ni] = be[bn * BN + wc * 64 + ni * 16 + l15];

#pragma unroll
    for (int mg = 0; mg < 4; ++mg) {
        const int grow = bm * BM + (mg >> 1) * 64 + wr * 32 + (mg & 1) * 16 + quad * 4;
#pragma unroll
        for (int ni = 0; ni < 4; ++ni) {
            const int gcol = bn * BN + wc * 64 + ni * 16 + l15;
            float* po = out + (size_t)grow * OUT + gcol;
#pragma unroll
            for (int r = 0; r < 4; ++r)
                po[(size_t)r * OUT] = acc[mg][ni][r] + bev[ni];
        }
    }
}

extern "C" void kernel_launch(void* const* d_in, const int* in_sizes, int n_in,
                              void* d_out, int out_size, void* d_ws, size_t ws_size,
                              hipStream_t stream) {
    const float* x    = (const float*)d_in[0];   // [8192,1024]
    const float* W    = (const float*)d_in[1];   // [1024,1024]
    const float* C    = (const float*)d_in[2];   // [1024,1024,4]
    const float* bias = (const float*)d_in[3];   // [1024]
    float* out = (float*)d_out;

    unsigned short* Bb = (unsigned short*)d_ws;                    // 8 MB
    float*          be = (float*)(Bb + (size_t)OUT * KDIM);        // 4 KB

    constexpr int LDS_BYTES = 3 * LDSBUF * 2;                      // 147456 = 144 KB
    static bool inited = false;
    if (!inited) {
        hipFuncSetAttribute(reinterpret_cast<const void*>(&gemm_kan),
                            hipFuncAttributeMaxDynamicSharedMemorySize, LDS_BYTES);
        inited = true;
    }

    prep_b<<<dim3(1024), dim3(256), 0, stream>>>(W, C, bias, Bb, be);

    gemm_kan<<<dim3(256), dim3(512), LDS_BYTES, stream>>>(x, Bb, be, out);
}